// Round 7
// baseline (204.110 us; speedup 1.0000x reference)
//
#include <hip/hip_runtime.h>
#include <hip/hip_bf16.h>

// Problem constants
#define B_   8
#define S_   1024
#define D_   768
#define H_   12
#define HD_  64
#define BS_  (B_*S_)     // 8192 rows
#define N3_  (3*D_)      // 2304

typedef __attribute__((ext_vector_type(8))) short short8;   // 8 x bf16 (4 VGPRs)
typedef __attribute__((ext_vector_type(4))) float f32x4;

__device__ __forceinline__ short8 ld8(const __hip_bfloat16* p) {
    return *reinterpret_cast<const short8*>(p);
}
__device__ __forceinline__ void st8(__hip_bfloat16* p, short8 v) {
    *reinterpret_cast<short8*>(p) = v;
}
__device__ __forceinline__ f32x4 mfma16(short8 a, short8 b, f32x4 c) {
    return __builtin_amdgcn_mfma_f32_16x16x32_bf16(a, b, c, 0, 0, 0);
}
// async global->LDS, 16B/lane; LDS dest = wave-uniform base + lane*16 (HW adds)
__device__ __forceinline__ void async16(const __hip_bfloat16* g, __hip_bfloat16* l) {
    __builtin_amdgcn_global_load_lds((const __attribute__((address_space(1))) void*)g,
                                     (__attribute__((address_space(3))) void*)l,
                                     16, 0, 0);
}
__device__ __forceinline__ float fast_exp2(float x) {
#if __has_builtin(__builtin_amdgcn_exp2f)
    return __builtin_amdgcn_exp2f(x);
#else
    return __expf(x * 0.69314718056f);
#endif
}

// ---------------- cast fp32 -> bf16 (flat) ----------------
__global__ void cast_f32_bf16(const float* __restrict__ in,
                              __hip_bfloat16* __restrict__ out, int n) {
    int i = (blockIdx.x * blockDim.x + threadIdx.x) * 4;
    if (i + 3 < n) {
        float4 v = *reinterpret_cast<const float4*>(in + i);
        out[i + 0] = __float2bfloat16(v.x);
        out[i + 1] = __float2bfloat16(v.y);
        out[i + 2] = __float2bfloat16(v.z);
        out[i + 3] = __float2bfloat16(v.w);
    }
}

// ---------------- transpose + cast: out[c][r] = in[r][c] ----------------
__global__ void transpose_cast(const float* __restrict__ in,
                               __hip_bfloat16* __restrict__ out, int R, int C) {
    __shared__ float tile[32][33];
    int c0 = blockIdx.x * 32, r0 = blockIdx.y * 32;
    for (int i = threadIdx.y; i < 32; i += 8) {
        tile[i][threadIdx.x] = in[(size_t)(r0 + i) * C + c0 + threadIdx.x];
    }
    __syncthreads();
    for (int i = threadIdx.y; i < 32; i += 8) {
        out[(size_t)(c0 + i) * R + r0 + threadIdx.x] =
            __float2bfloat16(tile[threadIdx.x][i]);
    }
}

// ---------------- QKV GEMM: BK=64 staged k-loop, [8192,768]x[768,2304] -----
// Q pre-scaled by 1/8*log2e for exp2 softmax. Row stride 64 bf16 = 128 B
// (bank-aligned), so chunk column is swizzled by row&7 both in staging and
// in the ds_read_b128 fragment loads.
__global__ __launch_bounds__(256)
void gemm_qkv(const __hip_bfloat16* __restrict__ A,
              const __hip_bfloat16* __restrict__ Bt,
              const float* __restrict__ bqkv,
              __hip_bfloat16* __restrict__ Qb,
              __hip_bfloat16* __restrict__ Kb,
              __hip_bfloat16* __restrict__ Vtb) {
    __shared__ __align__(16) char smem[128 * 132 * 2];   // 33 KB (union)
    __hip_bfloat16* As = (__hip_bfloat16*)smem;          // [128][64] swizzled
    __hip_bfloat16* Bs = As + 128 * 64;                  // [128][64] swizzled
    __hip_bfloat16* Ct = (__hip_bfloat16*)smem;          // [128][132] epilogue

    int tid = threadIdx.x, wave = tid >> 6, lane = tid & 63;
    int ln = lane & 15, quad = lane >> 4;
    int mb = blockIdx.y * 128, nb = blockIdx.x * 128;
    int wm = (wave >> 1) * 64, wn = (wave & 1) * 64;

    f32x4 acc[4][4];
#pragma unroll
    for (int i = 0; i < 4; ++i)
#pragma unroll
        for (int j = 0; j < 4; ++j) acc[i][j] = (f32x4){0.f, 0.f, 0.f, 0.f};

    for (int k = 0; k < D_; k += 64) {
#pragma unroll
        for (int it = 0; it < 4; ++it) {
            int c = it * 256 + tid;            // 16B chunk index [0,1024)
            int row = c >> 3, cc = c & 7;
            int csw = cc ^ (row & 7);
            async16(A + (size_t)(mb + row) * D_ + k + csw * 8,
                    As + it * 2048 + wave * 512);
            async16(Bt + (size_t)(nb + row) * D_ + k + csw * 8,
                    Bs + it * 2048 + wave * 512);
        }
        __syncthreads();   // drains vmcnt(0): staged tiles visible

#pragma unroll
        for (int ks = 0; ks < 2; ++ks) {
            short8 a[4], b[4];
#pragma unroll
            for (int i = 0; i < 4; ++i) {
                int row = wm + i * 16 + ln;
                a[i] = ld8(As + row * 64 + (((ks * 4 + quad) ^ (row & 7)) << 3));
            }
#pragma unroll
            for (int j = 0; j < 4; ++j) {
                int row = wn + j * 16 + ln;
                b[j] = ld8(Bs + row * 64 + (((ks * 4 + quad) ^ (row & 7)) << 3));
            }
#pragma unroll
            for (int i = 0; i < 4; ++i)
#pragma unroll
                for (int j = 0; j < 4; ++j)
                    acc[i][j] = mfma16(a[i], b[j], acc[i][j]);
        }
        __syncthreads();   // staging bufs reusable
    }

    // ---- epilogue: one pass through 33 KB LDS, coalesced 16B stores ----
    int which = blockIdx.x / 6;         // 0=Q, 1=K, 2=V
    int nbr = nb - which * D_;
    float qscale = (which == 0) ? (0.125f * 1.44269504089f) : 1.f;

#pragma unroll
    for (int j = 0; j < 4; ++j) {
        int col = wn + j * 16 + ln;
        float bias = bqkv[nb + col];
#pragma unroll
        for (int i = 0; i < 4; ++i)
#pragma unroll
            for (int r = 0; r < 4; ++r) {
                int row = wm + i * 16 + quad * 4 + r;
                __hip_bfloat16 v = __float2bfloat16((acc[i][j][r] + bias) * qscale);
                if (which != 2) Ct[row * 132 + col] = v;
                else            Ct[col * 132 + row] = v;    // [d][s]
            }
    }
    __syncthreads();

    int bb = mb >> 10, sb = mb & 1023;
    if (which != 2) {
        __hip_bfloat16* dst = (which == 0) ? Qb : Kb;
#pragma unroll
        for (int it = 0; it < 8; ++it) {
            int cc = it * 256 + tid;
            int row = cc >> 4, c8 = cc & 15;
            short8 v = ld8(Ct + row * 132 + c8 * 8);
            int gcol = nbr + c8 * 8;
            int h = gcol >> 6, d = gcol & 63;
            int s = sb + row;
            st8(dst + (((size_t)(bb * H_ + h)) * S_ + s) * HD_ + d, v);
        }
    } else {
#pragma unroll
        for (int it = 0; it < 8; ++it) {
            int cc = it * 256 + tid;
            int drow = cc >> 4, s8 = cc & 15;
            short8 v = ld8(Ct + drow * 132 + s8 * 8);
            int gd = nbr + drow;
            int h = gd >> 6, d = gd & 63;
            st8(Vtb + ((size_t)(bb * H_ + h) * HD_ + d) * S_ + sb + s8 * 8, v);
        }
    }
}

// ---------------- causal flash attention v3 (unchanged) --------------------
__global__ __launch_bounds__(256, 3)
void attn_flash3(const __hip_bfloat16* __restrict__ Q,
                 const __hip_bfloat16* __restrict__ K,
                 const __hip_bfloat16* __restrict__ Vt,
                 __hip_bfloat16* __restrict__ attnbf) {
    __shared__ __hip_bfloat16 Kbuf[2][64 * 64];
    __shared__ __hip_bfloat16 Vbuf[2][64 * 64];
    __shared__ __hip_bfloat16 Pbuf[4][32 * 72];

    int bh = blockIdx.y;
    int ip = blockIdx.x;                     // pair index 0..7
    int tid = threadIdx.x;
    int wave = tid >> 6, lane = tid & 63;
    int ln = lane & 15, quad = lane >> 4;
    int strip = (wave < 2) ? ip : (15 - ip);
    int qrow0 = strip * 64 + (wave & 1) * 32;

    const __hip_bfloat16* Qbh = Q + (size_t)bh * S_ * HD_;
    const __hip_bfloat16* Kbh = K + (size_t)bh * S_ * HD_;
    const __hip_bfloat16* Vbh = Vt + (size_t)bh * HD_ * S_;

    short8 aq[2][2];
#pragma unroll
    for (int rt = 0; rt < 2; ++rt)
#pragma unroll
        for (int ks = 0; ks < 2; ++ks)
            aq[rt][ks] = ld8(Qbh + (size_t)(qrow0 + rt * 16 + ln) * HD_ +
                             ks * 32 + quad * 8);

    f32x4 o[2][4];
    float l_run[2][4];
#pragma unroll
    for (int rt = 0; rt < 2; ++rt)
#pragma unroll
        for (int n = 0; n < 4; ++n) {
            o[rt][n] = (f32x4){0.f, 0.f, 0.f, 0.f};
            l_run[rt][n] = 0.f;
        }

    int last_kt = 15 - ip;

    auto stage = [&](int kt, int buf) {
        const __hip_bfloat16* gK = Kbh + (size_t)kt * 64 * HD_;
#pragma unroll
        for (int it = 0; it < 2; ++it) {
            int p = it * 256 + tid;
            int row = p >> 3;
            int csw = (p & 7) ^ (row & 7);
            async16(gK + row * HD_ + csw * 8,
                    &Kbuf[buf][it * 2048 + wave * 512]);
            async16(Vbh + (size_t)row * S_ + kt * 64 + csw * 8,
                    &Vbuf[buf][it * 2048 + wave * 512]);
        }
    };

    stage(0, 0);
    __syncthreads();
    int cur = 0;

    for (int kt = 0; kt <= last_kt; ++kt) {
        int kbase = kt * 64;
        if (kt < last_kt) stage(kt + 1, cur ^ 1);

        if (kbase <= qrow0 + 31) {
            const __hip_bfloat16* Kc = Kbuf[cur];
            const __hip_bfloat16* Vc = Vbuf[cur];

            f32x4 s[2][4];
#pragma unroll
            for (int rt = 0; rt < 2; ++rt)
#pragma unroll
                for (int j = 0; j < 4; ++j) s[rt][j] = (f32x4){0.f, 0.f, 0.f, 0.f};
#pragma unroll
            for (int j = 0; j < 4; ++j) {
                int row = j * 16 + ln;
#pragma unroll
                for (int ks = 0; ks < 2; ++ks) {
                    short8 bk = ld8(&Kc[row * 64 +
                                        (((ks * 4 + quad) ^ (row & 7)) << 3)]);
#pragma unroll
                    for (int rt = 0; rt < 2; ++rt)
                        s[rt][j] = mfma16(aq[rt][ks], bk, s[rt][j]);
                }
            }

            if (kbase + 63 > qrow0) {
#pragma unroll
                for (int rt = 0; rt < 2; ++rt)
#pragma unroll
                    for (int j = 0; j < 4; ++j) {
                        int key = kbase + j * 16 + ln;
#pragma unroll
                        for (int r = 0; r < 4; ++r) {
                            int q = qrow0 + rt * 16 + quad * 4 + r;
                            if (key > q) s[rt][j][r] = -INFINITY;
                        }
                    }
            }

#pragma unroll
            for (int rt = 0; rt < 2; ++rt)
#pragma unroll
                for (int j = 0; j < 4; ++j)
#pragma unroll
                    for (int r = 0; r < 4; ++r)
                        s[rt][j][r] = fast_exp2(s[rt][j][r]);
#pragma unroll
            for (int rt = 0; rt < 2; ++rt)
#pragma unroll
                for (int r = 0; r < 4; ++r)
                    l_run[rt][r] += (s[rt][0][r] + s[rt][1][r]) +
                                    (s[rt][2][r] + s[rt][3][r]);

#pragma unroll
            for (int rt = 0; rt < 2; ++rt)
#pragma unroll
                for (int j = 0; j < 4; ++j)
#pragma unroll
                    for (int r = 0; r < 4; ++r)
                        Pbuf[wave][(rt * 16 + quad * 4 + r) * 72 + j * 16 + ln] =
                            __float2bfloat16(s[rt][j][r]);
            asm volatile("s_waitcnt lgkmcnt(0)" ::: "memory");

            short8 ap[2][2];
#pragma unroll
            for (int rt = 0; rt < 2; ++rt)
#pragma unroll
                for (int ks = 0; ks < 2; ++ks)
                    ap[rt][ks] = ld8(&Pbuf[wave][(rt * 16 + ln) * 72 +
                                                 ks * 32 + quad * 8]);

#pragma unroll
            for (int n = 0; n < 4; ++n) {
                int row = n * 16 + ln;
#pragma unroll
                for (int ks = 0; ks < 2; ++ks) {
                    short8 bv = ld8(&Vc[row * 64 +
                                        (((ks * 4 + quad) ^ (row & 7)) << 3)]);
#pragma unroll
                    for (int rt = 0; rt < 2; ++rt)
                        o[rt][n] = mfma16(ap[rt][ks], bv, o[rt][n]);
                }
            }
        }

        __syncthreads();
        cur ^= 1;
    }

    int bb = bh / H_, h = bh - bb * H_;
#pragma unroll
    for (int rt = 0; rt < 2; ++rt)
#pragma unroll
        for (int r = 0; r < 4; ++r) {
            float l = l_run[rt][r];
            l += __shfl_xor(l, 1);
            l += __shfl_xor(l, 2);
            l += __shfl_xor(l, 4);
            l += __shfl_xor(l, 8);
            float inv = 1.f / l;
            int row = qrow0 + rt * 16 + quad * 4 + r;
#pragma unroll
            for (int n = 0; n < 4; ++n) {
                int col = h * 64 + n * 16 + ln;
                attnbf[((size_t)bb * S_ + row) * D_ + col] =
                    __float2bfloat16(o[rt][n][r] * inv);
            }
        }
}

// ---------------- out projection: BK=64 staged k-loop ----------------------
__global__ __launch_bounds__(256)
void gemm_out(const __hip_bfloat16* __restrict__ A,
              const __hip_bfloat16* __restrict__ Bt,
              const float* __restrict__ bias,
              float* __restrict__ Cout) {
    __shared__ __align__(16) __hip_bfloat16 As[128 * 64];
    __shared__ __align__(16) __hip_bfloat16 Bs[128 * 64];

    int tid = threadIdx.x, wave = tid >> 6, lane = tid & 63;
    int ln = lane & 15, quad = lane >> 4;
    int mb = blockIdx.y * 128, nb = blockIdx.x * 128;
    int wm = (wave >> 1) * 64, wn = (wave & 1) * 64;

    f32x4 acc[4][4];
#pragma unroll
    for (int i = 0; i < 4; ++i)
#pragma unroll
        for (int j = 0; j < 4; ++j) acc[i][j] = (f32x4){0.f, 0.f, 0.f, 0.f};

    for (int k = 0; k < D_; k += 64) {
#pragma unroll
        for (int it = 0; it < 4; ++it) {
            int c = it * 256 + tid;
            int row = c >> 3, cc = c & 7;
            int csw = cc ^ (row & 7);
            async16(A + (size_t)(mb + row) * D_ + k + csw * 8,
                    As + it * 2048 + wave * 512);
            async16(Bt + (size_t)(nb + row) * D_ + k + csw * 8,
                    Bs + it * 2048 + wave * 512);
        }
        __syncthreads();

#pragma unroll
        for (int ks = 0; ks < 2; ++ks) {
            short8 a[4], b[4];
#pragma unroll
            for (int i = 0; i < 4; ++i) {
                int row = wm + i * 16 + ln;
                a[i] = ld8(As + row * 64 + (((ks * 4 + quad) ^ (row & 7)) << 3));
            }
#pragma unroll
            for (int j = 0; j < 4; ++j) {
                int row = wn + j * 16 + ln;
                b[j] = ld8(Bs + row * 64 + (((ks * 4 + quad) ^ (row & 7)) << 3));
            }
#pragma unroll
            for (int i = 0; i < 4; ++i)
#pragma unroll
                for (int j = 0; j < 4; ++j)
                    acc[i][j] = mfma16(a[i], b[j], acc[i][j]);
        }
        __syncthreads();
    }

#pragma unroll
    for (int j = 0; j < 4; ++j) {
        int col = nb + wn + j * 16 + ln;
        float bv = bias[col];
#pragma unroll
        for (int i = 0; i < 4; ++i)
#pragma unroll
            for (int r = 0; r < 4; ++r) {
                int row = mb + wm + i * 16 + quad * 4 + r;
                Cout[(size_t)row * D_ + col] = acc[i][j][r] + bv;
            }
    }
}

// ---------------- launch ----------------
extern "C" void kernel_launch(void* const* d_in, const int* in_sizes, int n_in,
                              void* d_out, int out_size, void* d_ws, size_t ws_size,
                              hipStream_t stream) {
    const float* X    = (const float*)d_in[0];
    const float* Wqkv = (const float*)d_in[1];
    const float* bqkv = (const float*)d_in[2];
    const float* Wout = (const float*)d_in[3];
    const float* bout = (const float*)d_in[4];
    float* out = (float*)d_out;

    constexpr size_t SZ_XBF   = (size_t)BS_ * D_ * 2;
    constexpr size_t SZ_WQKVT = (size_t)N3_ * D_ * 2;
    constexpr size_t SZ_WOUTT = (size_t)D_ * D_ * 2;
    constexpr size_t SZ_QKV   = (size_t)B_ * H_ * S_ * HD_ * 2;

    char* w = (char*)d_ws;
    __hip_bfloat16* Xbf    = (__hip_bfloat16*)(w);
    __hip_bfloat16* WqkvT  = (__hip_bfloat16*)(w + SZ_XBF);
    __hip_bfloat16* WoutT  = (__hip_bfloat16*)(w + SZ_XBF + SZ_WQKVT);
    __hip_bfloat16* Qb     = (__hip_bfloat16*)(w + SZ_XBF + SZ_WQKVT + SZ_WOUTT);
    __hip_bfloat16* Kb     = (__hip_bfloat16*)(w + SZ_XBF + SZ_WQKVT + SZ_WOUTT + SZ_QKV);
    __hip_bfloat16* Vtb    = (__hip_bfloat16*)(w + SZ_XBF + SZ_WQKVT + SZ_WOUTT + 2*SZ_QKV);
    __hip_bfloat16* attnbf = (__hip_bfloat16*)(w + SZ_XBF + SZ_WQKVT + SZ_WOUTT + 3*SZ_QKV);
    (void)ws_size; (void)in_sizes; (void)n_in; (void)out_size;

    int nX = BS_ * D_;
    cast_f32_bf16<<<nX / (256 * 4), 256, 0, stream>>>(X, Xbf, nX);
    transpose_cast<<<dim3(N3_ / 32, D_ / 32), dim3(32, 8), 0, stream>>>(Wqkv, WqkvT, D_, N3_);
    transpose_cast<<<dim3(D_ / 32, D_ / 32), dim3(32, 8), 0, stream>>>(Wout, WoutT, D_, D_);

    gemm_qkv<<<dim3(N3_ / 128, BS_ / 128), 256, 0, stream>>>(Xbf, WqkvT, bqkv, Qb, Kb, Vtb);

    attn_flash3<<<dim3(8, B_ * H_), 256, 0, stream>>>(Qb, Kb, Vtb, attnbf);

    gemm_out<<<dim3(D_ / 128, BS_ / 128), 256, 0, stream>>>(attnbf, WoutT, bout, out);
}

// Round 8
// 192.651 us; speedup vs baseline: 1.0595x; 1.0595x over previous
//
#include <hip/hip_runtime.h>
#include <hip/hip_bf16.h>

// Problem constants
#define B_   8
#define S_   1024
#define D_   768
#define H_   12
#define HD_  64
#define BS_  (B_*S_)     // 8192 rows
#define N3_  (3*D_)      // 2304

typedef __attribute__((ext_vector_type(8))) short short8;   // 8 x bf16 (4 VGPRs)
typedef __attribute__((ext_vector_type(4))) float f32x4;

__device__ __forceinline__ short8 ld8(const __hip_bfloat16* p) {
    return *reinterpret_cast<const short8*>(p);
}
__device__ __forceinline__ void st8(__hip_bfloat16* p, short8 v) {
    *reinterpret_cast<short8*>(p) = v;
}
__device__ __forceinline__ f32x4 mfma16(short8 a, short8 b, f32x4 c) {
    return __builtin_amdgcn_mfma_f32_16x16x32_bf16(a, b, c, 0, 0, 0);
}
// async global->LDS, 16B/lane; LDS dest = wave-uniform base + lane*16 (HW adds)
__device__ __forceinline__ void async16(const __hip_bfloat16* g, __hip_bfloat16* l) {
    __builtin_amdgcn_global_load_lds((const __attribute__((address_space(1))) void*)g,
                                     (__attribute__((address_space(3))) void*)l,
                                     16, 0, 0);
}
__device__ __forceinline__ float fast_exp2(float x) {
#if __has_builtin(__builtin_amdgcn_exp2f)
    return __builtin_amdgcn_exp2f(x);
#else
    return __expf(x * 0.69314718056f);
#endif
}

// ---------------- cast fp32 -> bf16 (flat) ----------------
__global__ void cast_f32_bf16(const float* __restrict__ in,
                              __hip_bfloat16* __restrict__ out, int n) {
    int i = (blockIdx.x * blockDim.x + threadIdx.x) * 4;
    if (i + 3 < n) {
        float4 v = *reinterpret_cast<const float4*>(in + i);
        out[i + 0] = __float2bfloat16(v.x);
        out[i + 1] = __float2bfloat16(v.y);
        out[i + 2] = __float2bfloat16(v.z);
        out[i + 3] = __float2bfloat16(v.w);
    }
}

// ---------------- transpose + cast: out[c][r] = in[r][c] ----------------
__global__ void transpose_cast(const float* __restrict__ in,
                               __hip_bfloat16* __restrict__ out, int R, int C) {
    __shared__ float tile[32][33];
    int c0 = blockIdx.x * 32, r0 = blockIdx.y * 32;
    for (int i = threadIdx.y; i < 32; i += 8) {
        tile[i][threadIdx.x] = in[(size_t)(r0 + i) * C + c0 + threadIdx.x];
    }
    __syncthreads();
    for (int i = threadIdx.y; i < 32; i += 8) {
        out[(size_t)(c0 + i) * R + r0 + threadIdx.x] =
            __float2bfloat16(tile[threadIdx.x][i]);
    }
}

// ---------------- QKV GEMM: BK=32, double-buffered staging -----------------
// One __syncthreads per k-iter: prefetch of tile k+1 is issued before compute
// on tile k, so the vmcnt drain at the barrier is overlapped by compute.
// Swizzle: LDS chunk (row,cc) holds global chunk (row, cc^((row>>1)&3)).
__global__ __launch_bounds__(256)
void gemm_qkv(const __hip_bfloat16* __restrict__ A,
              const __hip_bfloat16* __restrict__ Bt,
              const float* __restrict__ bqkv,
              __hip_bfloat16* __restrict__ Qb,
              __hip_bfloat16* __restrict__ Kb,
              __hip_bfloat16* __restrict__ Vtb) {
    __shared__ __align__(16) char smem[128 * 132 * 2];   // 33 KB (union)
    // staging: buf b at smem + b*16384 (As 8 KB, Bs 8 KB)
    __hip_bfloat16* Ct = (__hip_bfloat16*)smem;          // [128][132] epilogue

    int tid = threadIdx.x, wave = tid >> 6, lane = tid & 63;
    int ln = lane & 15, quad = lane >> 4;
    int mb = blockIdx.y * 128, nb = blockIdx.x * 128;
    int wm = (wave >> 1) * 64, wn = (wave & 1) * 64;

    f32x4 acc[4][4];
#pragma unroll
    for (int i = 0; i < 4; ++i)
#pragma unroll
        for (int j = 0; j < 4; ++j) acc[i][j] = (f32x4){0.f, 0.f, 0.f, 0.f};

    auto stage = [&](int k, int buf) {
        __hip_bfloat16* Asb = (__hip_bfloat16*)(smem + buf * 16384);
        __hip_bfloat16* Bsb = Asb + 128 * 32;
#pragma unroll
        for (int it = 0; it < 2; ++it) {
            int c = it * 256 + tid;
            int row = c >> 2, cc = c & 3;
            int csw = cc ^ ((row >> 1) & 3);
            async16(A + (size_t)(mb + row) * D_ + k + csw * 8,
                    Asb + it * 2048 + wave * 512);
            async16(Bt + (size_t)(nb + row) * D_ + k + csw * 8,
                    Bsb + it * 2048 + wave * 512);
        }
    };

    stage(0, 0);
    int cur = 0;
    for (int k = 0; k < D_; k += 32) {
        __syncthreads();   // buf[cur] staged; buf[cur^1] free (all waves done)
        if (k + 32 < D_) stage(k + 32, cur ^ 1);   // prefetch in flight

        __hip_bfloat16* As = (__hip_bfloat16*)(smem + cur * 16384);
        __hip_bfloat16* Bs = As + 128 * 32;
        short8 a[4], b[4];
#pragma unroll
        for (int i = 0; i < 4; ++i) {
            int row = wm + i * 16 + ln;
            a[i] = ld8(As + row * 32 + ((quad ^ ((row >> 1) & 3)) << 3));
        }
#pragma unroll
        for (int j = 0; j < 4; ++j) {
            int row = wn + j * 16 + ln;
            b[j] = ld8(Bs + row * 32 + ((quad ^ ((row >> 1) & 3)) << 3));
        }
#pragma unroll
        for (int i = 0; i < 4; ++i)
#pragma unroll
            for (int j = 0; j < 4; ++j)
                acc[i][j] = mfma16(a[i], b[j], acc[i][j]);
        cur ^= 1;
    }
    __syncthreads();   // last compute done; LDS reusable for epilogue

    // ---- epilogue: one pass through 33 KB LDS, coalesced 16B stores ----
    int which = blockIdx.x / 6;         // 0=Q, 1=K, 2=V
    int nbr = nb - which * D_;
    float qscale = (which == 0) ? (0.125f * 1.44269504089f) : 1.f;

#pragma unroll
    for (int j = 0; j < 4; ++j) {
        int col = wn + j * 16 + ln;
        float bias = bqkv[nb + col];
#pragma unroll
        for (int i = 0; i < 4; ++i)
#pragma unroll
            for (int r = 0; r < 4; ++r) {
                int row = wm + i * 16 + quad * 4 + r;
                __hip_bfloat16 v = __float2bfloat16((acc[i][j][r] + bias) * qscale);
                if (which != 2) Ct[row * 132 + col] = v;
                else            Ct[col * 132 + row] = v;    // [d][s]
            }
    }
    __syncthreads();

    int bb = mb >> 10, sb = mb & 1023;
    if (which != 2) {
        __hip_bfloat16* dst = (which == 0) ? Qb : Kb;
#pragma unroll
        for (int it = 0; it < 8; ++it) {
            int cc = it * 256 + tid;
            int row = cc >> 4, c8 = cc & 15;
            short8 v = ld8(Ct + row * 132 + c8 * 8);
            int gcol = nbr + c8 * 8;
            int h = gcol >> 6, d = gcol & 63;
            int s = sb + row;
            st8(dst + (((size_t)(bb * H_ + h)) * S_ + s) * HD_ + d, v);
        }
    } else {
#pragma unroll
        for (int it = 0; it < 8; ++it) {
            int cc = it * 256 + tid;
            int drow = cc >> 4, s8 = cc & 15;
            short8 v = ld8(Ct + drow * 132 + s8 * 8);
            int gd = nbr + drow;
            int h = gd >> 6, d = gd & 63;
            st8(Vtb + ((size_t)(bb * H_ + h) * HD_ + d) * S_ + sb + s8 * 8, v);
        }
    }
}

// ---------------- causal flash attention v3 (unchanged) --------------------
__global__ __launch_bounds__(256, 3)
void attn_flash3(const __hip_bfloat16* __restrict__ Q,
                 const __hip_bfloat16* __restrict__ K,
                 const __hip_bfloat16* __restrict__ Vt,
                 __hip_bfloat16* __restrict__ attnbf) {
    __shared__ __hip_bfloat16 Kbuf[2][64 * 64];
    __shared__ __hip_bfloat16 Vbuf[2][64 * 64];
    __shared__ __hip_bfloat16 Pbuf[4][32 * 72];

    int bh = blockIdx.y;
    int ip = blockIdx.x;                     // pair index 0..7
    int tid = threadIdx.x;
    int wave = tid >> 6, lane = tid & 63;
    int ln = lane & 15, quad = lane >> 4;
    int strip = (wave < 2) ? ip : (15 - ip);
    int qrow0 = strip * 64 + (wave & 1) * 32;

    const __hip_bfloat16* Qbh = Q + (size_t)bh * S_ * HD_;
    const __hip_bfloat16* Kbh = K + (size_t)bh * S_ * HD_;
    const __hip_bfloat16* Vbh = Vt + (size_t)bh * HD_ * S_;

    short8 aq[2][2];
#pragma unroll
    for (int rt = 0; rt < 2; ++rt)
#pragma unroll
        for (int ks = 0; ks < 2; ++ks)
            aq[rt][ks] = ld8(Qbh + (size_t)(qrow0 + rt * 16 + ln) * HD_ +
                             ks * 32 + quad * 8);

    f32x4 o[2][4];
    float l_run[2][4];
#pragma unroll
    for (int rt = 0; rt < 2; ++rt)
#pragma unroll
        for (int n = 0; n < 4; ++n) {
            o[rt][n] = (f32x4){0.f, 0.f, 0.f, 0.f};
            l_run[rt][n] = 0.f;
        }

    int last_kt = 15 - ip;

    auto stage = [&](int kt, int buf) {
        const __hip_bfloat16* gK = Kbh + (size_t)kt * 64 * HD_;
#pragma unroll
        for (int it = 0; it < 2; ++it) {
            int p = it * 256 + tid;
            int row = p >> 3;
            int csw = (p & 7) ^ (row & 7);
            async16(gK + row * HD_ + csw * 8,
                    &Kbuf[buf][it * 2048 + wave * 512]);
            async16(Vbh + (size_t)row * S_ + kt * 64 + csw * 8,
                    &Vbuf[buf][it * 2048 + wave * 512]);
        }
    };

    stage(0, 0);
    __syncthreads();
    int cur = 0;

    for (int kt = 0; kt <= last_kt; ++kt) {
        int kbase = kt * 64;
        if (kt < last_kt) stage(kt + 1, cur ^ 1);

        if (kbase <= qrow0 + 31) {
            const __hip_bfloat16* Kc = Kbuf[cur];
            const __hip_bfloat16* Vc = Vbuf[cur];

            f32x4 s[2][4];
#pragma unroll
            for (int rt = 0; rt < 2; ++rt)
#pragma unroll
                for (int j = 0; j < 4; ++j) s[rt][j] = (f32x4){0.f, 0.f, 0.f, 0.f};
#pragma unroll
            for (int j = 0; j < 4; ++j) {
                int row = j * 16 + ln;
#pragma unroll
                for (int ks = 0; ks < 2; ++ks) {
                    short8 bk = ld8(&Kc[row * 64 +
                                        (((ks * 4 + quad) ^ (row & 7)) << 3)]);
#pragma unroll
                    for (int rt = 0; rt < 2; ++rt)
                        s[rt][j] = mfma16(aq[rt][ks], bk, s[rt][j]);
                }
            }

            if (kbase + 63 > qrow0) {
#pragma unroll
                for (int rt = 0; rt < 2; ++rt)
#pragma unroll
                    for (int j = 0; j < 4; ++j) {
                        int key = kbase + j * 16 + ln;
#pragma unroll
                        for (int r = 0; r < 4; ++r) {
                            int q = qrow0 + rt * 16 + quad * 4 + r;
                            if (key > q) s[rt][j][r] = -INFINITY;
                        }
                    }
            }

#pragma unroll
            for (int rt = 0; rt < 2; ++rt)
#pragma unroll
                for (int j = 0; j < 4; ++j)
#pragma unroll
                    for (int r = 0; r < 4; ++r)
                        s[rt][j][r] = fast_exp2(s[rt][j][r]);
#pragma unroll
            for (int rt = 0; rt < 2; ++rt)
#pragma unroll
                for (int r = 0; r < 4; ++r)
                    l_run[rt][r] += (s[rt][0][r] + s[rt][1][r]) +
                                    (s[rt][2][r] + s[rt][3][r]);

#pragma unroll
            for (int rt = 0; rt < 2; ++rt)
#pragma unroll
                for (int j = 0; j < 4; ++j)
#pragma unroll
                    for (int r = 0; r < 4; ++r)
                        Pbuf[wave][(rt * 16 + quad * 4 + r) * 72 + j * 16 + ln] =
                            __float2bfloat16(s[rt][j][r]);
            asm volatile("s_waitcnt lgkmcnt(0)" ::: "memory");

            short8 ap[2][2];
#pragma unroll
            for (int rt = 0; rt < 2; ++rt)
#pragma unroll
                for (int ks = 0; ks < 2; ++ks)
                    ap[rt][ks] = ld8(&Pbuf[wave][(rt * 16 + ln) * 72 +
                                                 ks * 32 + quad * 8]);

#pragma unroll
            for (int n = 0; n < 4; ++n) {
                int row = n * 16 + ln;
#pragma unroll
                for (int ks = 0; ks < 2; ++ks) {
                    short8 bv = ld8(&Vc[row * 64 +
                                        (((ks * 4 + quad) ^ (row & 7)) << 3)]);
#pragma unroll
                    for (int rt = 0; rt < 2; ++rt)
                        o[rt][n] = mfma16(ap[rt][ks], bv, o[rt][n]);
                }
            }
        }

        __syncthreads();
        cur ^= 1;
    }

    int bb = bh / H_, h = bh - bb * H_;
#pragma unroll
    for (int rt = 0; rt < 2; ++rt)
#pragma unroll
        for (int r = 0; r < 4; ++r) {
            float l = l_run[rt][r];
            l += __shfl_xor(l, 1);
            l += __shfl_xor(l, 2);
            l += __shfl_xor(l, 4);
            l += __shfl_xor(l, 8);
            float inv = 1.f / l;
            int row = qrow0 + rt * 16 + quad * 4 + r;
#pragma unroll
            for (int n = 0; n < 4; ++n) {
                int col = h * 64 + n * 16 + ln;
                attnbf[((size_t)bb * S_ + row) * D_ + col] =
                    __float2bfloat16(o[rt][n][r] * inv);
            }
        }
}

// ---------------- out projection: BK=32, double-buffered staging -----------
__global__ __launch_bounds__(256)
void gemm_out(const __hip_bfloat16* __restrict__ A,
              const __hip_bfloat16* __restrict__ Bt,
              const float* __restrict__ bias,
              float* __restrict__ Cout) {
    __shared__ __align__(16) char smem[2 * 16384];   // 2 x (As 8K + Bs 8K)

    int tid = threadIdx.x, wave = tid >> 6, lane = tid & 63;
    int ln = lane & 15, quad = lane >> 4;
    int mb = blockIdx.y * 128, nb = blockIdx.x * 128;
    int wm = (wave >> 1) * 64, wn = (wave & 1) * 64;

    f32x4 acc[4][4];
#pragma unroll
    for (int i = 0; i < 4; ++i)
#pragma unroll
        for (int j = 0; j < 4; ++j) acc[i][j] = (f32x4){0.f, 0.f, 0.f, 0.f};

    auto stage = [&](int k, int buf) {
        __hip_bfloat16* Asb = (__hip_bfloat16*)(smem + buf * 16384);
        __hip_bfloat16* Bsb = Asb + 128 * 32;
#pragma unroll
        for (int it = 0; it < 2; ++it) {
            int c = it * 256 + tid;
            int row = c >> 2, cc = c & 3;
            int csw = cc ^ ((row >> 1) & 3);
            async16(A + (size_t)(mb + row) * D_ + k + csw * 8,
                    Asb + it * 2048 + wave * 512);
            async16(Bt + (size_t)(nb + row) * D_ + k + csw * 8,
                    Bsb + it * 2048 + wave * 512);
        }
    };

    stage(0, 0);
    int cur = 0;
    for (int k = 0; k < D_; k += 32) {
        __syncthreads();
        if (k + 32 < D_) stage(k + 32, cur ^ 1);

        __hip_bfloat16* As = (__hip_bfloat16*)(smem + cur * 16384);
        __hip_bfloat16* Bs = As + 128 * 32;
        short8 a[4], b[4];
#pragma unroll
        for (int i = 0; i < 4; ++i) {
            int row = wm + i * 16 + ln;
            a[i] = ld8(As + row * 32 + ((quad ^ ((row >> 1) & 3)) << 3));
        }
#pragma unroll
        for (int j = 0; j < 4; ++j) {
            int row = wn + j * 16 + ln;
            b[j] = ld8(Bs + row * 32 + ((quad ^ ((row >> 1) & 3)) << 3));
        }
#pragma unroll
        for (int i = 0; i < 4; ++i)
#pragma unroll
            for (int j = 0; j < 4; ++j)
                acc[i][j] = mfma16(a[i], b[j], acc[i][j]);
        cur ^= 1;
    }

#pragma unroll
    for (int j = 0; j < 4; ++j) {
        int col = nb + wn + j * 16 + ln;
        float bv = bias[col];
#pragma unroll
        for (int i = 0; i < 4; ++i)
#pragma unroll
            for (int r = 0; r < 4; ++r) {
                int row = mb + wm + i * 16 + quad * 4 + r;
                Cout[(size_t)row * D_ + col] = acc[i][j][r] + bv;
            }
    }
}

// ---------------- launch ----------------
extern "C" void kernel_launch(void* const* d_in, const int* in_sizes, int n_in,
                              void* d_out, int out_size, void* d_ws, size_t ws_size,
                              hipStream_t stream) {
    const float* X    = (const float*)d_in[0];
    const float* Wqkv = (const float*)d_in[1];
    const float* bqkv = (const float*)d_in[2];
    const float* Wout = (const float*)d_in[3];
    const float* bout = (const float*)d_in[4];
    float* out = (float*)d_out;

    constexpr size_t SZ_XBF   = (size_t)BS_ * D_ * 2;
    constexpr size_t SZ_WQKVT = (size_t)N3_ * D_ * 2;
    constexpr size_t SZ_WOUTT = (size_t)D_ * D_ * 2;
    constexpr size_t SZ_QKV   = (size_t)B_ * H_ * S_ * HD_ * 2;

    char* w = (char*)d_ws;
    __hip_bfloat16* Xbf    = (__hip_bfloat16*)(w);
    __hip_bfloat16* WqkvT  = (__hip_bfloat16*)(w + SZ_XBF);
    __hip_bfloat16* WoutT  = (__hip_bfloat16*)(w + SZ_XBF + SZ_WQKVT);
    __hip_bfloat16* Qb     = (__hip_bfloat16*)(w + SZ_XBF + SZ_WQKVT + SZ_WOUTT);
    __hip_bfloat16* Kb     = (__hip_bfloat16*)(w + SZ_XBF + SZ_WQKVT + SZ_WOUTT + SZ_QKV);
    __hip_bfloat16* Vtb    = (__hip_bfloat16*)(w + SZ_XBF + SZ_WQKVT + SZ_WOUTT + 2*SZ_QKV);
    __hip_bfloat16* attnbf = (__hip_bfloat16*)(w + SZ_XBF + SZ_WQKVT + SZ_WOUTT + 3*SZ_QKV);
    (void)ws_size; (void)in_sizes; (void)n_in; (void)out_size;

    int nX = BS_ * D_;
    cast_f32_bf16<<<nX / (256 * 4), 256, 0, stream>>>(X, Xbf, nX);
    transpose_cast<<<dim3(N3_ / 32, D_ / 32), dim3(32, 8), 0, stream>>>(Wqkv, WqkvT, D_, N3_);
    transpose_cast<<<dim3(D_ / 32, D_ / 32), dim3(32, 8), 0, stream>>>(Wout, WoutT, D_, D_);

    gemm_qkv<<<dim3(N3_ / 128, BS_ / 128), 256, 0, stream>>>(Xbf, WqkvT, bqkv, Qb, Kb, Vtb);

    attn_flash3<<<dim3(8, B_ * H_), 256, 0, stream>>>(Qb, Kb, Vtb, attnbf);

    gemm_out<<<dim3(D_ / 128, BS_ / 128), 256, 0, stream>>>(attnbf, WoutT, bout, out);
}

// Round 9
// 192.392 us; speedup vs baseline: 1.0609x; 1.0013x over previous
//
#include <hip/hip_runtime.h>
#include <hip/hip_bf16.h>

// Problem constants
#define B_   8
#define S_   1024
#define D_   768
#define H_   12
#define HD_  64
#define BS_  (B_*S_)     // 8192 rows
#define N3_  (3*D_)      // 2304

typedef __attribute__((ext_vector_type(8))) short short8;   // 8 x bf16 (4 VGPRs)
typedef __attribute__((ext_vector_type(4))) float f32x4;

__device__ __forceinline__ short8 ld8(const __hip_bfloat16* p) {
    return *reinterpret_cast<const short8*>(p);
}
__device__ __forceinline__ void st8(__hip_bfloat16* p, short8 v) {
    *reinterpret_cast<short8*>(p) = v;
}
__device__ __forceinline__ f32x4 mfma16(short8 a, short8 b, f32x4 c) {
    return __builtin_amdgcn_mfma_f32_16x16x32_bf16(a, b, c, 0, 0, 0);
}
// async global->LDS, 16B/lane; LDS dest = wave-uniform base + lane*16 (HW adds)
__device__ __forceinline__ void async16(const __hip_bfloat16* g, __hip_bfloat16* l) {
    __builtin_amdgcn_global_load_lds((const __attribute__((address_space(1))) void*)g,
                                     (__attribute__((address_space(3))) void*)l,
                                     16, 0, 0);
}
__device__ __forceinline__ float fast_exp2(float x) {
#if __has_builtin(__builtin_amdgcn_exp2f)
    return __builtin_amdgcn_exp2f(x);
#else
    return __expf(x * 0.69314718056f);
#endif
}

// ---------------- cast fp32 -> bf16 (flat) ----------------
__global__ void cast_f32_bf16(const float* __restrict__ in,
                              __hip_bfloat16* __restrict__ out, int n) {
    int i = (blockIdx.x * blockDim.x + threadIdx.x) * 4;
    if (i + 3 < n) {
        float4 v = *reinterpret_cast<const float4*>(in + i);
        out[i + 0] = __float2bfloat16(v.x);
        out[i + 1] = __float2bfloat16(v.y);
        out[i + 2] = __float2bfloat16(v.z);
        out[i + 3] = __float2bfloat16(v.w);
    }
}

// ---------------- transpose + cast: out[c][r] = in[r][c] ----------------
__global__ void transpose_cast(const float* __restrict__ in,
                               __hip_bfloat16* __restrict__ out, int R, int C) {
    __shared__ float tile[32][33];
    int c0 = blockIdx.x * 32, r0 = blockIdx.y * 32;
    for (int i = threadIdx.y; i < 32; i += 8) {
        tile[i][threadIdx.x] = in[(size_t)(r0 + i) * C + c0 + threadIdx.x];
    }
    __syncthreads();
    for (int i = threadIdx.y; i < 32; i += 8) {
        out[(size_t)(c0 + i) * R + r0 + threadIdx.x] =
            __float2bfloat16(tile[threadIdx.x][i]);
    }
}

// ---------------- QKV GEMM: BK=32, TRIPLE-buffered, raw barrier + vmcnt(4) --
// Prefetch distance = 2 compute phases; steady-state wait is vmcnt(4) (never
// 0), so the L2 latency of the staging burst is fully overlapped. 3x16KB
// rotating slots; last k-iter peeled with vmcnt(0).
__global__ __launch_bounds__(256)
void gemm_qkv(const __hip_bfloat16* __restrict__ A,
              const __hip_bfloat16* __restrict__ Bt,
              const float* __restrict__ bqkv,
              __hip_bfloat16* __restrict__ Qb,
              __hip_bfloat16* __restrict__ Kb,
              __hip_bfloat16* __restrict__ Vtb) {
    __shared__ __align__(16) char smem[49152];           // 3 x (As 8K + Bs 8K)
    __hip_bfloat16* Ct = (__hip_bfloat16*)smem;          // [128][132] epilogue

    int tid = threadIdx.x, wave = tid >> 6, lane = tid & 63;
    int ln = lane & 15, quad = lane >> 4;
    int mb = blockIdx.y * 128, nb = blockIdx.x * 128;
    int wm = (wave >> 1) * 64, wn = (wave & 1) * 64;

    f32x4 acc[4][4];
#pragma unroll
    for (int i = 0; i < 4; ++i)
#pragma unroll
        for (int j = 0; j < 4; ++j) acc[i][j] = (f32x4){0.f, 0.f, 0.f, 0.f};

    auto stage = [&](int k, int bufoff) {   // 4 async16 per wave
        __hip_bfloat16* Asb = (__hip_bfloat16*)(smem + bufoff);
        __hip_bfloat16* Bsb = Asb + 128 * 32;
#pragma unroll
        for (int it = 0; it < 2; ++it) {
            int c = it * 256 + tid;
            int row = c >> 2, cc = c & 3;
            int csw = cc ^ ((row >> 1) & 3);
            async16(A + (size_t)(mb + row) * D_ + k + csw * 8,
                    Asb + it * 2048 + wave * 512);
            async16(Bt + (size_t)(nb + row) * D_ + k + csw * 8,
                    Bsb + it * 2048 + wave * 512);
        }
    };

    auto compute = [&](int bufoff) {
        __hip_bfloat16* As = (__hip_bfloat16*)(smem + bufoff);
        __hip_bfloat16* Bs = As + 128 * 32;
        short8 a[4], b[4];
#pragma unroll
        for (int i = 0; i < 4; ++i) {
            int row = wm + i * 16 + ln;
            a[i] = ld8(As + row * 32 + ((quad ^ ((row >> 1) & 3)) << 3));
        }
#pragma unroll
        for (int j = 0; j < 4; ++j) {
            int row = wn + j * 16 + ln;
            b[j] = ld8(Bs + row * 32 + ((quad ^ ((row >> 1) & 3)) << 3));
        }
#pragma unroll
        for (int i = 0; i < 4; ++i)
#pragma unroll
            for (int j = 0; j < 4; ++j)
                acc[i][j] = mfma16(a[i], b[j], acc[i][j]);
    };

    stage(0, 0);
    stage(32, 16384);
    int cb = 0;
    for (int k = 0; k < D_ - 32; k += 32) {
        asm volatile("s_waitcnt vmcnt(4)" ::: "memory");  // oldest stage done
        asm volatile("s_barrier" ::: "memory");           // visible to all
        if (k + 64 < D_) {
            int sb = cb + 32768; if (sb >= 49152) sb -= 49152;
            stage(k + 64, sb);                            // distance-2 prefetch
        }
        compute(cb);
        cb += 16384; if (cb >= 49152) cb = 0;
    }
    asm volatile("s_waitcnt vmcnt(0)" ::: "memory");      // peeled last iter
    asm volatile("s_barrier" ::: "memory");
    compute(cb);
    __syncthreads();   // all compute done; LDS reusable for epilogue

    // ---- epilogue: one pass through LDS, coalesced 16B stores ----
    int which = blockIdx.x / 6;         // 0=Q, 1=K, 2=V
    int nbr = nb - which * D_;
    float qscale = (which == 0) ? (0.125f * 1.44269504089f) : 1.f;

#pragma unroll
    for (int j = 0; j < 4; ++j) {
        int col = wn + j * 16 + ln;
        float bias = bqkv[nb + col];
#pragma unroll
        for (int i = 0; i < 4; ++i)
#pragma unroll
            for (int r = 0; r < 4; ++r) {
                int row = wm + i * 16 + quad * 4 + r;
                __hip_bfloat16 v = __float2bfloat16((acc[i][j][r] + bias) * qscale);
                if (which != 2) Ct[row * 132 + col] = v;
                else            Ct[col * 132 + row] = v;    // [d][s]
            }
    }
    __syncthreads();

    int bb = mb >> 10, sb = mb & 1023;
    if (which != 2) {
        __hip_bfloat16* dst = (which == 0) ? Qb : Kb;
#pragma unroll
        for (int it = 0; it < 8; ++it) {
            int cc = it * 256 + tid;
            int row = cc >> 4, c8 = cc & 15;
            short8 v = ld8(Ct + row * 132 + c8 * 8);
            int gcol = nbr + c8 * 8;
            int h = gcol >> 6, d = gcol & 63;
            int s = sb + row;
            st8(dst + (((size_t)(bb * H_ + h)) * S_ + s) * HD_ + d, v);
        }
    } else {
#pragma unroll
        for (int it = 0; it < 8; ++it) {
            int cc = it * 256 + tid;
            int drow = cc >> 4, s8 = cc & 15;
            short8 v = ld8(Ct + drow * 132 + s8 * 8);
            int gd = nbr + drow;
            int h = gd >> 6, d = gd & 63;
            st8(Vtb + ((size_t)(bb * H_ + h) * HD_ + d) * S_ + sb + s8 * 8, v);
        }
    }
}

// ---------------- causal flash attention v3 (unchanged) --------------------
__global__ __launch_bounds__(256, 3)
void attn_flash3(const __hip_bfloat16* __restrict__ Q,
                 const __hip_bfloat16* __restrict__ K,
                 const __hip_bfloat16* __restrict__ Vt,
                 __hip_bfloat16* __restrict__ attnbf) {
    __shared__ __hip_bfloat16 Kbuf[2][64 * 64];
    __shared__ __hip_bfloat16 Vbuf[2][64 * 64];
    __shared__ __hip_bfloat16 Pbuf[4][32 * 72];

    int bh = blockIdx.y;
    int ip = blockIdx.x;                     // pair index 0..7
    int tid = threadIdx.x;
    int wave = tid >> 6, lane = tid & 63;
    int ln = lane & 15, quad = lane >> 4;
    int strip = (wave < 2) ? ip : (15 - ip);
    int qrow0 = strip * 64 + (wave & 1) * 32;

    const __hip_bfloat16* Qbh = Q + (size_t)bh * S_ * HD_;
    const __hip_bfloat16* Kbh = K + (size_t)bh * S_ * HD_;
    const __hip_bfloat16* Vbh = Vt + (size_t)bh * HD_ * S_;

    short8 aq[2][2];
#pragma unroll
    for (int rt = 0; rt < 2; ++rt)
#pragma unroll
        for (int ks = 0; ks < 2; ++ks)
            aq[rt][ks] = ld8(Qbh + (size_t)(qrow0 + rt * 16 + ln) * HD_ +
                             ks * 32 + quad * 8);

    f32x4 o[2][4];
    float l_run[2][4];
#pragma unroll
    for (int rt = 0; rt < 2; ++rt)
#pragma unroll
        for (int n = 0; n < 4; ++n) {
            o[rt][n] = (f32x4){0.f, 0.f, 0.f, 0.f};
            l_run[rt][n] = 0.f;
        }

    int last_kt = 15 - ip;

    auto stage = [&](int kt, int buf) {
        const __hip_bfloat16* gK = Kbh + (size_t)kt * 64 * HD_;
#pragma unroll
        for (int it = 0; it < 2; ++it) {
            int p = it * 256 + tid;
            int row = p >> 3;
            int csw = (p & 7) ^ (row & 7);
            async16(gK + row * HD_ + csw * 8,
                    &Kbuf[buf][it * 2048 + wave * 512]);
            async16(Vbh + (size_t)row * S_ + kt * 64 + csw * 8,
                    &Vbuf[buf][it * 2048 + wave * 512]);
        }
    };

    stage(0, 0);
    __syncthreads();
    int cur = 0;

    for (int kt = 0; kt <= last_kt; ++kt) {
        int kbase = kt * 64;
        if (kt < last_kt) stage(kt + 1, cur ^ 1);

        if (kbase <= qrow0 + 31) {
            const __hip_bfloat16* Kc = Kbuf[cur];
            const __hip_bfloat16* Vc = Vbuf[cur];

            f32x4 s[2][4];
#pragma unroll
            for (int rt = 0; rt < 2; ++rt)
#pragma unroll
                for (int j = 0; j < 4; ++j) s[rt][j] = (f32x4){0.f, 0.f, 0.f, 0.f};
#pragma unroll
            for (int j = 0; j < 4; ++j) {
                int row = j * 16 + ln;
#pragma unroll
                for (int ks = 0; ks < 2; ++ks) {
                    short8 bk = ld8(&Kc[row * 64 +
                                        (((ks * 4 + quad) ^ (row & 7)) << 3)]);
#pragma unroll
                    for (int rt = 0; rt < 2; ++rt)
                        s[rt][j] = mfma16(aq[rt][ks], bk, s[rt][j]);
                }
            }

            if (kbase + 63 > qrow0) {
#pragma unroll
                for (int rt = 0; rt < 2; ++rt)
#pragma unroll
                    for (int j = 0; j < 4; ++j) {
                        int key = kbase + j * 16 + ln;
#pragma unroll
                        for (int r = 0; r < 4; ++r) {
                            int q = qrow0 + rt * 16 + quad * 4 + r;
                            if (key > q) s[rt][j][r] = -INFINITY;
                        }
                    }
            }

#pragma unroll
            for (int rt = 0; rt < 2; ++rt)
#pragma unroll
                for (int j = 0; j < 4; ++j)
#pragma unroll
                    for (int r = 0; r < 4; ++r)
                        s[rt][j][r] = fast_exp2(s[rt][j][r]);
#pragma unroll
            for (int rt = 0; rt < 2; ++rt)
#pragma unroll
                for (int r = 0; r < 4; ++r)
                    l_run[rt][r] += (s[rt][0][r] + s[rt][1][r]) +
                                    (s[rt][2][r] + s[rt][3][r]);

#pragma unroll
            for (int rt = 0; rt < 2; ++rt)
#pragma unroll
                for (int j = 0; j < 4; ++j)
#pragma unroll
                    for (int r = 0; r < 4; ++r)
                        Pbuf[wave][(rt * 16 + quad * 4 + r) * 72 + j * 16 + ln] =
                            __float2bfloat16(s[rt][j][r]);
            asm volatile("s_waitcnt lgkmcnt(0)" ::: "memory");

            short8 ap[2][2];
#pragma unroll
            for (int rt = 0; rt < 2; ++rt)
#pragma unroll
                for (int ks = 0; ks < 2; ++ks)
                    ap[rt][ks] = ld8(&Pbuf[wave][(rt * 16 + ln) * 72 +
                                                 ks * 32 + quad * 8]);

#pragma unroll
            for (int n = 0; n < 4; ++n) {
                int row = n * 16 + ln;
#pragma unroll
                for (int ks = 0; ks < 2; ++ks) {
                    short8 bv = ld8(&Vc[row * 64 +
                                        (((ks * 4 + quad) ^ (row & 7)) << 3)]);
#pragma unroll
                    for (int rt = 0; rt < 2; ++rt)
                        o[rt][n] = mfma16(ap[rt][ks], bv, o[rt][n]);
                }
            }
        }

        __syncthreads();
        cur ^= 1;
    }

    int bb = bh / H_, h = bh - bb * H_;
#pragma unroll
    for (int rt = 0; rt < 2; ++rt)
#pragma unroll
        for (int r = 0; r < 4; ++r) {
            float l = l_run[rt][r];
            l += __shfl_xor(l, 1);
            l += __shfl_xor(l, 2);
            l += __shfl_xor(l, 4);
            l += __shfl_xor(l, 8);
            float inv = 1.f / l;
            int row = qrow0 + rt * 16 + quad * 4 + r;
#pragma unroll
            for (int n = 0; n < 4; ++n) {
                int col = h * 64 + n * 16 + ln;
                attnbf[((size_t)bb * S_ + row) * D_ + col] =
                    __float2bfloat16(o[rt][n][r] * inv);
            }
        }
}

// ---------------- out projection: BK=32, triple-buffered pipeline ----------
__global__ __launch_bounds__(256)
void gemm_out(const __hip_bfloat16* __restrict__ A,
              const __hip_bfloat16* __restrict__ Bt,
              const float* __restrict__ bias,
              float* __restrict__ Cout) {
    __shared__ __align__(16) char smem[49152];   // 3 x (As 8K + Bs 8K)

    int tid = threadIdx.x, wave = tid >> 6, lane = tid & 63;
    int ln = lane & 15, quad = lane >> 4;
    int mb = blockIdx.y * 128, nb = blockIdx.x * 128;
    int wm = (wave >> 1) * 64, wn = (wave & 1) * 64;

    f32x4 acc[4][4];
#pragma unroll
    for (int i = 0; i < 4; ++i)
#pragma unroll
        for (int j = 0; j < 4; ++j) acc[i][j] = (f32x4){0.f, 0.f, 0.f, 0.f};

    auto stage = [&](int k, int bufoff) {
        __hip_bfloat16* Asb = (__hip_bfloat16*)(smem + bufoff);
        __hip_bfloat16* Bsb = Asb + 128 * 32;
#pragma unroll
        for (int it = 0; it < 2; ++it) {
            int c = it * 256 + tid;
            int row = c >> 2, cc = c & 3;
            int csw = cc ^ ((row >> 1) & 3);
            async16(A + (size_t)(mb + row) * D_ + k + csw * 8,
                    Asb + it * 2048 + wave * 512);
            async16(Bt + (size_t)(nb + row) * D_ + k + csw * 8,
                    Bsb + it * 2048 + wave * 512);
        }
    };

    auto compute = [&](int bufoff) {
        __hip_bfloat16* As = (__hip_bfloat16*)(smem + bufoff);
        __hip_bfloat16* Bs = As + 128 * 32;
        short8 a[4], b[4];
#pragma unroll
        for (int i = 0; i < 4; ++i) {
            int row = wm + i * 16 + ln;
            a[i] = ld8(As + row * 32 + ((quad ^ ((row >> 1) & 3)) << 3));
        }
#pragma unroll
        for (int j = 0; j < 4; ++j) {
            int row = wn + j * 16 + ln;
            b[j] = ld8(Bs + row * 32 + ((quad ^ ((row >> 1) & 3)) << 3));
        }
#pragma unroll
        for (int i = 0; i < 4; ++i)
#pragma unroll
            for (int j = 0; j < 4; ++j)
                acc[i][j] = mfma16(a[i], b[j], acc[i][j]);
    };

    stage(0, 0);
    stage(32, 16384);
    int cb = 0;
    for (int k = 0; k < D_ - 32; k += 32) {
        asm volatile("s_waitcnt vmcnt(4)" ::: "memory");
        asm volatile("s_barrier" ::: "memory");
        if (k + 64 < D_) {
            int sb = cb + 32768; if (sb >= 49152) sb -= 49152;
            stage(k + 64, sb);
        }
        compute(cb);
        cb += 16384; if (cb >= 49152) cb = 0;
    }
    asm volatile("s_waitcnt vmcnt(0)" ::: "memory");
    asm volatile("s_barrier" ::: "memory");
    compute(cb);

#pragma unroll
    for (int j = 0; j < 4; ++j) {
        int col = nb + wn + j * 16 + ln;
        float bv = bias[col];
#pragma unroll
        for (int i = 0; i < 4; ++i)
#pragma unroll
            for (int r = 0; r < 4; ++r) {
                int row = mb + wm + i * 16 + quad * 4 + r;
                Cout[(size_t)row * D_ + col] = acc[i][j][r] + bv;
            }
    }
}

// ---------------- launch ----------------
extern "C" void kernel_launch(void* const* d_in, const int* in_sizes, int n_in,
                              void* d_out, int out_size, void* d_ws, size_t ws_size,
                              hipStream_t stream) {
    const float* X    = (const float*)d_in[0];
    const float* Wqkv = (const float*)d_in[1];
    const float* bqkv = (const float*)d_in[2];
    const float* Wout = (const float*)d_in[3];
    const float* bout = (const float*)d_in[4];
    float* out = (float*)d_out;

    constexpr size_t SZ_XBF   = (size_t)BS_ * D_ * 2;
    constexpr size_t SZ_WQKVT = (size_t)N3_ * D_ * 2;
    constexpr size_t SZ_WOUTT = (size_t)D_ * D_ * 2;
    constexpr size_t SZ_QKV   = (size_t)B_ * H_ * S_ * HD_ * 2;

    char* w = (char*)d_ws;
    __hip_bfloat16* Xbf    = (__hip_bfloat16*)(w);
    __hip_bfloat16* WqkvT  = (__hip_bfloat16*)(w + SZ_XBF);
    __hip_bfloat16* WoutT  = (__hip_bfloat16*)(w + SZ_XBF + SZ_WQKVT);
    __hip_bfloat16* Qb     = (__hip_bfloat16*)(w + SZ_XBF + SZ_WQKVT + SZ_WOUTT);
    __hip_bfloat16* Kb     = (__hip_bfloat16*)(w + SZ_XBF + SZ_WQKVT + SZ_WOUTT + SZ_QKV);
    __hip_bfloat16* Vtb    = (__hip_bfloat16*)(w + SZ_XBF + SZ_WQKVT + SZ_WOUTT + 2*SZ_QKV);
    __hip_bfloat16* attnbf = (__hip_bfloat16*)(w + SZ_XBF + SZ_WQKVT + SZ_WOUTT + 3*SZ_QKV);
    (void)ws_size; (void)in_sizes; (void)n_in; (void)out_size;

    int nX = BS_ * D_;
    cast_f32_bf16<<<nX / (256 * 4), 256, 0, stream>>>(X, Xbf, nX);
    transpose_cast<<<dim3(N3_ / 32, D_ / 32), dim3(32, 8), 0, stream>>>(Wqkv, WqkvT, D_, N3_);
    transpose_cast<<<dim3(D_ / 32, D_ / 32), dim3(32, 8), 0, stream>>>(Wout, WoutT, D_, D_);

    gemm_qkv<<<dim3(N3_ / 128, BS_ / 128), 256, 0, stream>>>(Xbf, WqkvT, bqkv, Qb, Kb, Vtb);

    attn_flash3<<<dim3(8, B_ * H_), 256, 0, stream>>>(Qb, Kb, Vtb, attnbf);

    gemm_out<<<dim3(D_ / 128, BS_ / 128), 256, 0, stream>>>(attnbf, WoutT, bout, out);
}